// Round 6
// baseline (527.123 us; speedup 1.0000x reference)
//
#include <hip/hip_runtime.h>
#include <hip/hip_bf16.h>
#include <stdint.h>

#define SEQ     4096
#define NBATCH  16
#define DMODEL  768
#define NHEAD   12
#define HDIM    64
#define WINSZ   64
#define SHIFT_T 32
#define QKV_N   (3*DMODEL)   // 2304

typedef __attribute__((ext_vector_type(8)))  short bf16x8;
typedef __attribute__((ext_vector_type(4)))  float f32x4;
typedef __attribute__((ext_vector_type(16))) float f32x16;

static __device__ __forceinline__ unsigned short f2bf(float f) {
  union { float f; unsigned u; } v; v.f = f;
  unsigned r = v.u + 0x7fffu + ((v.u >> 16) & 1u);
  return (unsigned short)(r >> 16);
}

#define G2L(gp, lp) __builtin_amdgcn_global_load_lds( \
    (const __attribute__((address_space(1))) unsigned*)(const void*)(gp), \
    (__attribute__((address_space(3))) unsigned*)(void*)(lp), 16, 0, 0)

// ---- cast x (fp32) -> bf16 with +SHIFT roll fused
__global__ void k_cvt_x(const float* __restrict__ x, unsigned short* __restrict__ xb,
                        long long c0, long long n8) {
  for (long long i = (long long)blockIdx.x*blockDim.x + threadIdx.x; i < n8;
       i += (long long)gridDim.x*blockDim.x) {
    long long e = i*8;
    int d = (int)(e % DMODEL);
    long long gt = c0 + e / DMODEL;
    int t = (int)(gt & (SEQ-1));
    long long b = gt >> 12;
    int ts = (t - SHIFT_T) & (SEQ-1);
    const float* src = x + (((b << 12) + ts) * (long long)DMODEL + d);
    float4 a0 = *(const float4*)src;
    float4 a1 = *(const float4*)(src + 4);
    bf16x8 o;
    o[0]=(short)f2bf(a0.x); o[1]=(short)f2bf(a0.y); o[2]=(short)f2bf(a0.z); o[3]=(short)f2bf(a0.w);
    o[4]=(short)f2bf(a1.x); o[5]=(short)f2bf(a1.y); o[6]=(short)f2bf(a1.z); o[7]=(short)f2bf(a1.w);
    *(bf16x8*)(xb + e) = o;
  }
}

__global__ void k_cvt_w(const float* __restrict__ w, unsigned short* __restrict__ wb, int n8) {
  int i = blockIdx.x*blockDim.x + threadIdx.x;
  if (i >= n8) return;
  float4 a0 = ((const float4*)w)[2*i];
  float4 a1 = ((const float4*)w)[2*i+1];
  bf16x8 o;
  o[0]=(short)f2bf(a0.x); o[1]=(short)f2bf(a0.y); o[2]=(short)f2bf(a0.z); o[3]=(short)f2bf(a0.w);
  o[4]=(short)f2bf(a1.x); o[5]=(short)f2bf(a1.y); o[6]=(short)f2bf(a1.z); o[7]=(short)f2bf(a1.w);
  ((bf16x8*)wb)[i] = o;
}

// ---- 256x256 bf16 GEMM, round-5 4-phase/K64-tile schedule, 32x32x16 MFMA.
// C[m,n] = sum_k A[m,k]*B[n,k] + bias[n].
// LDS: 2 x 64KB dbuf; per buf: A 256x64 (4x8KB regions of 64 rows) @0, B @32768.
// Rows 128 B; swizzle involution per region: P ^= ((P>>7)&7)<<4.
// Staging: 8 G2L/tile (FIFO B0,B1 | B2,B3 | A0,A2 | A1,A3), one tile ahead.
// Waits: vmcnt(4) at ph2-end gates ph3/ph4 (A1/A3); vmcnt(2) at ph4-end gates
// next tile's ph1/ph2 (A0/A2 + all B). Phases = (mf-pair x ks-pair):
// ph1 mf01/ks01, ph2 mf01/ks23, ph3 mf23/ks01, ph4 mf23/ks23.
// B-frags (8 x b128) register-cached across the tile.
#define MFMA32(a,b,c) __builtin_amdgcn_mfma_f32_32x32x16_bf16(a,b,c,0,0,0)
#define MFMA16(a,b,c) __builtin_amdgcn_mfma_f32_16x16x32_bf16(a,b,c,0,0,0)
#define LDS8(p) (*(const bf16x8*)(p))

template<int MODE>
__global__ __launch_bounds__(512, 1)
void k_gemm256(const unsigned short* __restrict__ A, const unsigned short* __restrict__ Bw,
               const float* __restrict__ bias, unsigned short* __restrict__ Cb,
               float* __restrict__ Cf, int M, int N, int K, int nTN, long long c0) {
  __shared__ char lds[131072];
  const int nt = K >> 6;                      // K64 tiles (768 -> 12, even)
  int nwg = gridDim.x;
  int cpx = nwg >> 3;
  int wg  = (blockIdx.x & 7) * cpx + (blockIdx.x >> 3);   // XCD-contiguous
  int bm = wg / nTN, bn = wg - bm*nTN;
  long long m0 = (long long)bm * 256;
  int n0 = bn * 256;
  int tid = threadIdx.x;
  int lane = tid & 63, wid = tid >> 6;
  int wr = wid >> 2, wc = wid & 3;            // 2M x 4N waves, each 128x64 of C
  int l31 = lane & 31, h = lane >> 5;

  // staging sources: linear LDS dest L, inverse-swizzled global source
  const long long K2 = 2LL * K;
  int L  = tid * 16;
  int Ls = L ^ (((L >> 7) & 7) << 4);
  int srow = Ls >> 7, scol = Ls & 127;        // row 0..63 within region, byte col
  const char* gAr0 = (const char*)A + (m0 +       srow) * K2 + scol;
  const char* gAr1 = (const char*)A + (m0 +  64 + srow) * K2 + scol;
  const char* gAr2 = (const char*)A + (m0 + 128 + srow) * K2 + scol;
  const char* gAr3 = (const char*)A + (m0 + 192 + srow) * K2 + scol;
  const char* gBr0 = (const char*)Bw + (long long)(n0 +       srow) * K2 + scol;
  const char* gBr1 = (const char*)Bw + (long long)(n0 +  64 + srow) * K2 + scol;
  const char* gBr2 = (const char*)Bw + (long long)(n0 + 128 + srow) * K2 + scol;
  const char* gBr3 = (const char*)Bw + (long long)(n0 + 192 + srow) * K2 + scol;

  // frag-read bases. A row = wr*128 + mf*32 + l31 -> addr row*128 (+ mf*4096),
  // chunk byte = (ks*32 + h*16) ^ ((l31&7)<<4). Uniform 8 lanes/chunk-pos.
  int key  = (l31 & 7) << 4;
  int arow = (wr*128 + l31) * 128;            // + mf*4096
  int brow = 32768 + (wc*64 + l31) * 128;     // + nf*4096
  int kc0 = (  0 + h*16) ^ key;
  int kc1 = ( 32 + h*16) ^ key;
  int kc2 = ( 64 + h*16) ^ key;
  int kc3 = ( 96 + h*16) ^ key;

  f32x16 acc[4][2];
  #pragma unroll
  for (int i = 0; i < 4; ++i)
    #pragma unroll
    for (int j = 0; j < 2; ++j)
      #pragma unroll
      for (int e = 0; e < 16; ++e) acc[i][j][e] = 0.f;

#define BARR __builtin_amdgcn_s_barrier()
#define SBAR __builtin_amdgcn_sched_barrier(0)
#define LGK0 do { asm volatile("s_waitcnt lgkmcnt(0)" ::: "memory"); SBAR; } while(0)

#define TILE(RD, ST, DOSTAGE, WBSTR, DOWA) do {                               \
    const char* rb = (RD); char* stb = (ST);                                  \
    bf16x8 b00,b10,b01,b11,b02,b12,b03,b13;                                   \
    { /* ph1: mf{0,1} x ks{0,1}; stage B0,B1 */                               \
      bf16x8 a00 = LDS8(rb + arow        + kc0);                              \
      bf16x8 a01 = LDS8(rb + arow        + kc1);                              \
      bf16x8 a10 = LDS8(rb + arow + 4096 + kc0);                              \
      bf16x8 a11 = LDS8(rb + arow + 4096 + kc1);                              \
      b00 = LDS8(rb + brow        + kc0);  b10 = LDS8(rb + brow + 4096 + kc0);\
      b01 = LDS8(rb + brow        + kc1);  b11 = LDS8(rb + brow + 4096 + kc1);\
      if (DOSTAGE) { G2L(gBr0, stb + 32768 + L); G2L(gBr1, stb + 40960 + L); }\
      SBAR; BARR; LGK0;                                                       \
      __builtin_amdgcn_s_setprio(1);                                          \
      acc[0][0]=MFMA32(a00,b00,acc[0][0]); acc[0][1]=MFMA32(a00,b10,acc[0][1]);\
      acc[1][0]=MFMA32(a10,b00,acc[1][0]); acc[1][1]=MFMA32(a10,b10,acc[1][1]);\
      acc[0][0]=MFMA32(a01,b01,acc[0][0]); acc[0][1]=MFMA32(a01,b11,acc[0][1]);\
      acc[1][0]=MFMA32(a11,b01,acc[1][0]); acc[1][1]=MFMA32(a11,b11,acc[1][1]);\
      __builtin_amdgcn_s_setprio(0); SBAR; BARR;                              \
    }                                                                         \
    { /* ph2: mf{0,1} x ks{2,3}; stage B2,B3; vmcnt gates ph3/ph4 */          \
      bf16x8 a02 = LDS8(rb + arow        + kc2);                              \
      bf16x8 a03 = LDS8(rb + arow        + kc3);                              \
      bf16x8 a12 = LDS8(rb + arow + 4096 + kc2);                              \
      bf16x8 a13 = LDS8(rb + arow + 4096 + kc3);                              \
      b02 = LDS8(rb + brow        + kc2);  b12 = LDS8(rb + brow + 4096 + kc2);\
      b03 = LDS8(rb + brow        + kc3);  b13 = LDS8(rb + brow + 4096 + kc3);\
      if (DOSTAGE) { G2L(gBr2, stb + 49152 + L); G2L(gBr3, stb + 57344 + L); }\
      SBAR; BARR; LGK0;                                                       \
      __builtin_amdgcn_s_setprio(1);                                          \
      acc[0][0]=MFMA32(a02,b02,acc[0][0]); acc[0][1]=MFMA32(a02,b12,acc[0][1]);\
      acc[1][0]=MFMA32(a12,b02,acc[1][0]); acc[1][1]=MFMA32(a12,b12,acc[1][1]);\
      acc[0][0]=MFMA32(a03,b03,acc[0][0]); acc[0][1]=MFMA32(a03,b13,acc[0][1]);\
      acc[1][0]=MFMA32(a13,b03,acc[1][0]); acc[1][1]=MFMA32(a13,b13,acc[1][1]);\
      __builtin_amdgcn_s_setprio(0); SBAR;                                    \
      asm volatile(WBSTR ::: "memory"); SBAR; BARR;                           \
    }                                                                         \
    { /* ph3: mf{2,3} x ks{0,1}; stage A0,A2 */                               \
      bf16x8 a20 = LDS8(rb + arow +  8192 + kc0);                             \
      bf16x8 a21 = LDS8(rb + arow +  8192 + kc1);                             \
      bf16x8 a30 = LDS8(rb + arow + 12288 + kc0);                             \
      bf16x8 a31 = LDS8(rb + arow + 12288 + kc1);                             \
      if (DOSTAGE) { G2L(gAr0, stb + L); G2L(gAr2, stb + 16384 + L); }        \
      SBAR; BARR; LGK0;                                                       \
      __builtin_amdgcn_s_setprio(1);                                          \
      acc[2][0]=MFMA32(a20,b00,acc[2][0]); acc[2][1]=MFMA32(a20,b10,acc[2][1]);\
      acc[3][0]=MFMA32(a30,b00,acc[3][0]); acc[3][1]=MFMA32(a30,b10,acc[3][1]);\
      acc[2][0]=MFMA32(a21,b01,acc[2][0]); acc[2][1]=MFMA32(a21,b11,acc[2][1]);\
      acc[3][0]=MFMA32(a31,b01,acc[3][0]); acc[3][1]=MFMA32(a31,b11,acc[3][1]);\
      __builtin_amdgcn_s_setprio(0); SBAR; BARR;                              \
    }                                                                         \
    { /* ph4: mf{2,3} x ks{2,3}; stage A1,A3; boundary wait */                \
      bf16x8 a22 = LDS8(rb + arow +  8192 + kc2);                             \
      bf16x8 a23 = LDS8(rb + arow +  8192 + kc3);                             \
      bf16x8 a32 = LDS8(rb + arow + 12288 + kc2);                             \
      bf16x8 a33 = LDS8(rb + arow + 12288 + kc3);                             \
      if (DOSTAGE) { G2L(gAr1, stb + 8192 + L); G2L(gAr3, stb + 24576 + L);   \
                     gAr0 += 128; gAr1 += 128; gAr2 += 128; gAr3 += 128;      \
                     gBr0 += 128; gBr1 += 128; gBr2 += 128; gBr3 += 128; }    \
      SBAR; BARR; LGK0;                                                       \
      __builtin_amdgcn_s_setprio(1);                                          \
      acc[2][0]=MFMA32(a22,b02,acc[2][0]); acc[2][1]=MFMA32(a22,b12,acc[2][1]);\
      acc[3][0]=MFMA32(a32,b02,acc[3][0]); acc[3][1]=MFMA32(a32,b12,acc[3][1]);\
      acc[2][0]=MFMA32(a23,b03,acc[2][0]); acc[2][1]=MFMA32(a23,b13,acc[2][1]);\
      acc[3][0]=MFMA32(a33,b03,acc[3][0]); acc[3][1]=MFMA32(a33,b13,acc[3][1]);\
      __builtin_amdgcn_s_setprio(0); SBAR;                                    \
      if (DOWA) { asm volatile("s_waitcnt vmcnt(2)" ::: "memory"); }          \
      SBAR; BARR;                                                             \
    }                                                                         \
  } while (0)

  // ---- prologue: stage tile 0 (FIFO B0,B1,B2,B3, A0, A2, A1, A3)
  G2L(gBr0, lds + 32768 + L); G2L(gBr1, lds + 40960 + L);
  G2L(gBr2, lds + 49152 + L); G2L(gBr3, lds + 57344 + L);
  G2L(gAr0, lds + L);         G2L(gAr2, lds + 16384 + L);
  G2L(gAr1, lds + 8192 + L);  G2L(gAr3, lds + 24576 + L);
  gAr0 += 128; gAr1 += 128; gAr2 += 128; gAr3 += 128;
  gBr0 += 128; gBr1 += 128; gBr2 += 128; gBr3 += 128;
  asm volatile("s_waitcnt vmcnt(2)" ::: "memory");
  SBAR; BARR;

  char* const bufA = lds;
  char* const bufB = lds + 65536;
  for (int i = 0; i < (nt - 2) / 2; ++i) {
    TILE(bufA, bufB, 1, "s_waitcnt vmcnt(4)", 1);
    TILE(bufB, bufA, 1, "s_waitcnt vmcnt(4)", 1);
  }
  TILE(bufA, bufB, 1, "s_waitcnt vmcnt(4)", 1);
  TILE(bufB, bufA, 0, "s_waitcnt vmcnt(0)", 0);
#undef TILE

  // ---- epilogue: 32x32 C layout: col = l31, row = (reg&3) + 8*(reg>>2) + 4*h
  #pragma unroll
  for (int mt = 0; mt < 4; ++mt) {
    #pragma unroll
    for (int nf = 0; nf < 2; ++nf) {
      int n = n0 + wc*64 + nf*32 + l31;
      float bv = bias[n];
      #pragma unroll
      for (int reg = 0; reg < 16; ++reg) {
        int rin = (reg & 3) + 8*(reg >> 2) + 4*h;
        long long m = m0 + wr*128 + mt*32 + rin;
        float v = acc[mt][nf][reg] + bv;
        if (MODE == 0) {
          Cb[m * (long long)N + n] = f2bf(v);
        } else {
          long long gm = c0 + m;
          long long om = (gm & ~(long long)(SEQ-1)) | ((gm - SHIFT_T) & (long long)(SEQ-1));
          Cf[om * (long long)N + n] = v;
        }
      }
    }
  }
}

// ---- per-(window,head) attention: S = QK^T*scale + rel_bias, softmax, O = P V
__global__ __launch_bounds__(256, 4)
void k_attn(const unsigned short* __restrict__ qkv, const float* __restrict__ rel_bias,
            unsigned short* __restrict__ y) {
  int w = blockIdx.x / NHEAD;
  int h = blockIdx.x - w*NHEAD;
  __shared__ unsigned short sQ[64*72], sK[64*72], sV[64*72];
  __shared__ unsigned short sP[4][16*72];
  __shared__ float rb[128];
  int tid = threadIdx.x, lane = tid & 63, wid = tid >> 6;
  int cl = lane & 15, g4 = lane >> 4;

  if (tid < 2*WINSZ - 1) rb[tid] = rel_bias[h*(2*WINSZ-1) + tid];

  const unsigned short* base = qkv + (long long)w*WINSZ*QKV_N + h*HDIM;
  #pragma unroll
  for (int pass = 0; pass < 2; ++pass) {
    int row = (tid >> 3) + pass*32;
    int ch  = tid & 7;
    const unsigned short* src = base + (long long)row*QKV_N + ch*8;
    *(bf16x8*)(sQ + row*72 + ch*8) = *(const bf16x8*)(src);
    *(bf16x8*)(sK + row*72 + ch*8) = *(const bf16x8*)(src + DMODEL);
    *(bf16x8*)(sV + row*72 + ch*8) = *(const bf16x8*)(src + 2*DMODEL);
  }
  __syncthreads();

  f32x4 sc[4];
  #pragma unroll
  for (int nt = 0; nt < 4; ++nt) sc[nt] = (f32x4){0.f,0.f,0.f,0.f};
  #pragma unroll
  for (int kk = 0; kk < 2; ++kk) {
    bf16x8 aq = *(const bf16x8*)(sQ + (wid*16 + cl)*72 + kk*32 + g4*8);
    #pragma unroll
    for (int nt = 0; nt < 4; ++nt) {
      bf16x8 bk = *(const bf16x8*)(sK + (nt*16 + cl)*72 + kk*32 + g4*8);
      sc[nt] = MFMA16(aq, bk, sc[nt]);
    }
  }

  float pv[4][4];
  #pragma unroll
  for (int r = 0; r < 4; ++r) {
    int qi = wid*16 + g4*4 + r;
    float mx = -1e30f;
    #pragma unroll
    for (int nt = 0; nt < 4; ++nt) {
      int kj = nt*16 + cl;
      float v = sc[nt][r]*0.125f + rb[kj - qi + (WINSZ-1)];
      pv[nt][r] = v;
      mx = fmaxf(mx, v);
    }
    #pragma unroll
    for (int m = 1; m < 16; m <<= 1) mx = fmaxf(mx, __shfl_xor(mx, m, 64));
    float sum = 0.f;
    #pragma unroll
    for (int nt = 0; nt < 4; ++nt) { float e = __expf(pv[nt][r]-mx); pv[nt][r] = e; sum += e; }
    #pragma unroll
    for (int m = 1; m < 16; m <<= 1) sum += __shfl_xor(sum, m, 64);
    float inv = 1.f / sum;
    #pragma unroll
    for (int nt = 0; nt < 4; ++nt)
      sP[wid][(g4*4+r)*72 + nt*16 + cl] = f2bf(pv[nt][r]*inv);
  }

  f32x4 o[4];
  #pragma unroll
  for (int nt = 0; nt < 4; ++nt) o[nt] = (f32x4){0.f,0.f,0.f,0.f};
  #pragma unroll
  for (int kk = 0; kk < 2; ++kk) {
    bf16x8 ap = *(const bf16x8*)(&sP[wid][cl*72 + kk*32 + g4*8]);
    #pragma unroll
    for (int nt = 0; nt < 4; ++nt) {
      bf16x8 bv;
      #pragma unroll
      for (int j = 0; j < 8; ++j)
        bv[j] = (short)sV[(kk*32 + g4*8 + j)*72 + nt*16 + cl];
      o[nt] = MFMA16(ap, bv, o[nt]);
    }
  }

  long long tokbase = (long long)w * WINSZ;
  #pragma unroll
  for (int nt = 0; nt < 4; ++nt)
    #pragma unroll
    for (int r = 0; r < 4; ++r) {
      int row = wid*16 + g4*4 + r;
      y[(tokbase + row) * (long long)DMODEL + h*HDIM + nt*16 + cl] = f2bf(o[nt][r]);
    }
}

extern "C" void kernel_launch(void* const* d_in, const int* in_sizes, int n_in,
                              void* d_out, int out_size, void* d_ws, size_t ws_size,
                              hipStream_t stream) {
  const float* x      = (const float*)d_in[0];
  const float* qkv_w  = (const float*)d_in[1];
  const float* qkv_b  = (const float*)d_in[2];
  const float* proj_w = (const float*)d_in[3];
  const float* proj_b = (const float*)d_in[4];
  const float* rel_b  = (const float*)d_in[5];
  float* out = (float*)d_out;

  const long long NTOK = (long long)NBATCH * SEQ;    // 65536
  const size_t wbytes = (size_t)QKV_N*DMODEL*2 + (size_t)DMODEL*DMODEL*2;

  int C = 16;
  for (int c : {1, 2, 4, 8, 16}) {
    size_t tpc = (size_t)NTOK / c;
    size_t need = tpc*QKV_N*2 + tpc*DMODEL*2 + wbytes;
    if (need <= ws_size) { C = c; break; }
  }
  long long tpc = NTOK / C;

  char* ws = (char*)d_ws;
  unsigned short* qkvb = (unsigned short*)ws;
  unsigned short* xb   = (unsigned short*)(ws + (size_t)tpc*QKV_N*2);
  unsigned short* wq   = (unsigned short*)(ws + (size_t)tpc*QKV_N*2 + (size_t)tpc*DMODEL*2);
  unsigned short* wp   = wq + (size_t)QKV_N*DMODEL;

  k_cvt_w<<<(QKV_N*DMODEL/8 + 255)/256, 256, 0, stream>>>(qkv_w, wq, QKV_N*DMODEL/8);
  k_cvt_w<<<(DMODEL*DMODEL/8 + 255)/256, 256, 0, stream>>>(proj_w, wp, DMODEL*DMODEL/8);

  for (int c = 0; c < C; ++c) {
    long long c0 = (long long)c * tpc;
    long long n8 = tpc * DMODEL / 8;
    int cvtGrid = (int)((n8 + 255) / 256); if (cvtGrid > 2048) cvtGrid = 2048;
    k_cvt_x<<<cvtGrid, 256, 0, stream>>>(x, xb, c0, n8);

    int mT = (int)(tpc / 256);
    k_gemm256<0><<<mT * (QKV_N/256), 512, 0, stream>>>(xb, wq, qkv_b, qkvb, nullptr,
                                                       (int)tpc, QKV_N, DMODEL, QKV_N/256, c0);
    k_attn<<<(int)(tpc/WINSZ) * NHEAD, 256, 0, stream>>>(qkvb, rel_b, xb /*reuse as y*/);
    k_gemm256<1><<<mT * (DMODEL/256), 512, 0, stream>>>(xb, wp, proj_b, nullptr, out,
                                                        (int)tpc, DMODEL, DMODEL, DMODEL/256, c0);
  }
}